// Round 1
// baseline (641.438 us; speedup 1.0000x reference)
//
#include <hip/hip_runtime.h>

#define B_ 4
#define L_ 2048
#define E_ 512
#define H_ 8
#define HD_ 64
#define NROW (B_*L_)        // 8192 flat rows
#define SZ (NROW*E_)        // 4194304 elements per (8192,512) matrix
#define NH (B_*H_)          // 32 batch-heads
#define EPS_ 1e-6f

// C[m][n] = sum_k X[m][k]*W[n][k] + bias[n]   (i.e. X @ W^T + b)
// grid (NROW/64, E_/64), block 256. 64x64 C tile, 4x4 per thread, K-chunks of 16.
__global__ __launch_bounds__(256) void gemm_xwt(const float* __restrict__ X,
    const float* __restrict__ W, const float* __restrict__ bias,
    float* __restrict__ C) {
  __shared__ float sX[16][64];
  __shared__ float sW[16][64];
  const int bm = blockIdx.x * 64;
  const int bn = blockIdx.y * 64;
  const int tid = threadIdx.x;
  const int tx = tid & 15, ty = tid >> 4;
  float acc[4][4] = {};
  for (int k0 = 0; k0 < E_; k0 += 16) {
#pragma unroll
    for (int i = 0; i < 4; ++i) {
      int idx = tid + i * 256;          // 0..1023
      int m = idx >> 4, k = idx & 15;
      sX[k][m] = X[(bm + m) * E_ + k0 + k];
      sW[k][m] = W[(bn + m) * E_ + k0 + k];
    }
    __syncthreads();
#pragma unroll
    for (int k = 0; k < 16; ++k) {
      float xr[4], wr[4];
#pragma unroll
      for (int i = 0; i < 4; ++i) xr[i] = sX[k][ty * 4 + i];
#pragma unroll
      for (int j = 0; j < 4; ++j) wr[j] = sW[k][tx * 4 + j];
#pragma unroll
      for (int i = 0; i < 4; ++i)
#pragma unroll
        for (int j = 0; j < 4; ++j)
          acc[i][j] = fmaf(xr[i], wr[j], acc[i][j]);
    }
    __syncthreads();
  }
#pragma unroll
  for (int i = 0; i < 4; ++i) {
    int m = bm + ty * 4 + i;
#pragma unroll
    for (int j = 0; j < 4; ++j) {
      int n = bn + tx * 4 + j;
      C[m * E_ + n] = acc[i][j] + bias[n];
    }
  }
}

// In-place softmax over contiguous 64-element head slices. One wave per slice.
__global__ __launch_bounds__(256) void softmax64(float* __restrict__ X) {
  int idx = blockIdx.x * 256 + threadIdx.x;
  float v = X[idx];
  float m = v;
#pragma unroll
  for (int off = 32; off; off >>= 1) m = fmaxf(m, __shfl_xor(m, off, 64));
  float e = __expf(v - m);
  float s = e;
#pragma unroll
  for (int off = 32; off; off >>= 1) s += __shfl_xor(s, off, 64);
  X[idx] = e / s;
}

// Per batch-head n: M[n] = K_n^T V_n (64x64), Ksum[n], Vsum[n].
// grid (NH, 8): blockIdx.y splits L into 8 chunks of 256; atomicAdd merge.
__global__ __launch_bounds__(256) void kv_reduce(const float* __restrict__ K,
    const float* __restrict__ V, float* __restrict__ Mout,
    float* __restrict__ Ksum, float* __restrict__ Vsum) {
  const int n = blockIdx.x;
  const int b = n >> 3, h = n & 7;
  const int tid = threadIdx.x;
  const int td = tid & 15, te = tid >> 4;
  __shared__ float sK[2][64], sV[2][64];
  float acc[4][4] = {};
  float srow = 0.f;
  const int which = tid >> 7;          // 0 -> stage K, 1 -> stage V
  const int sub = tid & 127;
  const int lr = sub >> 6, d = sub & 63;
  const int l0beg = blockIdx.y * (L_ / 8);
  for (int l0 = l0beg; l0 < l0beg + L_ / 8; l0 += 2) {
    int l = l0 + lr;
    int flat = (l * B_ + b) * E_ + h * HD_ + d;
    float val = which ? V[flat] : K[flat];
    __syncthreads();
    if (which) sV[lr][d] = val; else sK[lr][d] = val;
    __syncthreads();
#pragma unroll
    for (int p = 0; p < 2; ++p) {
      float kk[4], vv[4];
#pragma unroll
      for (int i = 0; i < 4; ++i) kk[i] = sK[p][td * 4 + i];
#pragma unroll
      for (int j = 0; j < 4; ++j) vv[j] = sV[p][te * 4 + j];
#pragma unroll
      for (int i = 0; i < 4; ++i)
#pragma unroll
        for (int j = 0; j < 4; ++j)
          acc[i][j] = fmaf(kk[i], vv[j], acc[i][j]);
      if (tid < 64) srow += sK[p][tid];
      else if (tid < 128) srow += sV[p][tid - 64];
    }
  }
#pragma unroll
  for (int i = 0; i < 4; ++i)
#pragma unroll
    for (int j = 0; j < 4; ++j)
      atomicAdd(&Mout[n * 4096 + (td * 4 + i) * 64 + te * 4 + j], acc[i][j]);
  if (tid < 64) atomicAdd(&Ksum[n * 64 + tid], srow);
  else if (tid < 128) atomicAdd(&Vsum[n * 64 + tid - 64], srow);
}

// A[r, h*64+e] = (2*q^T M + 62*Vsum) / max(2*q.Ksum + 62*L, EPS). One wave per (r,h).
__global__ __launch_bounds__(256) void apply_attn(const float* __restrict__ Q,
    const float* __restrict__ Mmat, const float* __restrict__ Ksum,
    const float* __restrict__ Vsum, float* __restrict__ A) {
  const int gw = (blockIdx.x * 256 + threadIdx.x) >> 6;   // r*8 + h
  const int lane = threadIdx.x & 63;
  const int r = gw >> 3, h = gw & 7;
  const int b = r & (B_ - 1);               // r = l*B + b
  const int n = b * H_ + h;
  const int base = r * E_ + h * HD_;
  const float q = Q[base + lane];
  // denominator: 2 * q.Ksum + 62*L
  float kd = q * Ksum[n * 64 + lane];
#pragma unroll
  for (int off = 32; off; off >>= 1) kd += __shfl_xor(kd, off, 64);
  const float den = fmaxf(2.f * kd + 62.f * (float)L_, EPS_);
  // numerator: 2 * sum_d q_d * M[d][lane] + 62 * Vsum[lane]
  float num0 = 0.f;
  const float* Mp = Mmat + n * 4096;
#pragma unroll 8
  for (int d = 0; d < 64; ++d) {
    float qd = __shfl(q, d, 64);
    num0 = fmaf(qd, Mp[d * 64 + lane], num0);
  }
  float num = 2.f * num0 + 62.f * Vsum[n * 64 + lane];
  A[base + lane] = num / den;
}

extern "C" void kernel_launch(void* const* d_in, const int* in_sizes, int n_in,
                              void* d_out, int out_size, void* d_ws, size_t ws_size,
                              hipStream_t stream) {
  const float* query = (const float*)d_in[0];
  const float* Wq = (const float*)d_in[1];
  const float* bq = (const float*)d_in[2];
  const float* Wk = (const float*)d_in[3];
  const float* bk = (const float*)d_in[4];
  const float* Wv = (const float*)d_in[5];
  const float* bv = (const float*)d_in[6];
  const float* Wo = (const float*)d_in[7];
  const float* bo = (const float*)d_in[8];
  float* out = (float*)d_out;

  float* ws = (float*)d_ws;
  float* Q  = ws;
  float* Kb = ws + (size_t)SZ;
  float* Vb = ws + 2 * (size_t)SZ;
  float* A  = ws + 3 * (size_t)SZ;
  float* M  = ws + 4 * (size_t)SZ;          // NH * 64 * 64
  float* Ks = M + NH * 4096;                // NH * 64
  float* Vs = Ks + NH * 64;                 // NH * 64

  dim3 gg(NROW / 64, E_ / 64);
  gemm_xwt<<<gg, 256, 0, stream>>>(query, Wq, bq, Q);
  gemm_xwt<<<gg, 256, 0, stream>>>(query, Wk, bk, Kb);
  gemm_xwt<<<gg, 256, 0, stream>>>(query, Wv, bv, Vb);
  softmax64<<<SZ / 256, 256, 0, stream>>>(Q);
  softmax64<<<SZ / 256, 256, 0, stream>>>(Kb);
  hipMemsetAsync(M, 0, (size_t)(NH * 4096 + 2 * NH * 64) * sizeof(float), stream);
  kv_reduce<<<dim3(NH, 8), 256, 0, stream>>>(Kb, Vb, M, Ks, Vs);
  apply_attn<<<NROW * H_ / 4, 256, 0, stream>>>(Q, M, Ks, Vs, A);
  gemm_xwt<<<gg, 256, 0, stream>>>(A, Wo, bo, out);
}

// Round 2
// 203.064 us; speedup vs baseline: 3.1588x; 3.1588x over previous
//
#include <hip/hip_runtime.h>

#define B_ 4
#define L_ 2048
#define E_ 512
#define H_ 8
#define NROW (B_*L_)        // 8192 flat rows
#define SZ (NROW*E_)        // 4194304
#define NH (B_*H_)          // 32 batch-heads

typedef unsigned short u16;
typedef unsigned int u32;
typedef __attribute__((ext_vector_type(8))) __bf16 bf16x8;
typedef __attribute__((ext_vector_type(8))) u16 u16x8;
typedef __attribute__((ext_vector_type(4))) float f32x4;

__device__ __forceinline__ u16 f2bf(float f) {
  union { float f; u32 u; } v; v.f = f;
  u32 r = v.u + 0x7FFFu + ((v.u >> 16) & 1u);   // RNE
  return (u16)(r >> 16);
}
__device__ __forceinline__ float bf2f(u16 s) {
  union { u32 u; float f; } v; v.u = ((u32)s) << 16;
  return v.f;
}
// async global->LDS, 16B per lane. lds dest = wave-uniform base + lane*16.
__device__ __forceinline__ void async16(const u16* g, u16* l) {
  __builtin_amdgcn_global_load_lds(
      (const __attribute__((address_space(1))) u32*)g,
      (__attribute__((address_space(3))) u32*)l, 16, 0, 0);
}

// ---------- fp32 -> bf16 converters ----------
__global__ __launch_bounds__(256) void cvt_x(const float* __restrict__ X,
                                             u16* __restrict__ Y) {
  const int i0 = (blockIdx.x * 256 + threadIdx.x) * 8;
  f32x4 a = *(const f32x4*)(X + i0);
  f32x4 b = *(const f32x4*)(X + i0 + 4);
  u16x8 o;
#pragma unroll
  for (int j = 0; j < 4; ++j) { o[j] = f2bf(a[j]); o[4 + j] = f2bf(b[j]); }
  *(u16x8*)(Y + i0) = o;
}

__global__ __launch_bounds__(256) void cvt_w(const float* __restrict__ W0,
    const float* __restrict__ W1, const float* __restrict__ W2,
    const float* __restrict__ W3, u16* __restrict__ Y0, u16* __restrict__ Y1,
    u16* __restrict__ Y2, u16* __restrict__ Y3) {
  const int s = blockIdx.y;
  const float* W = (s == 0) ? W0 : (s == 1) ? W1 : (s == 2) ? W2 : W3;
  u16* Y = (s == 0) ? Y0 : (s == 1) ? Y1 : (s == 2) ? Y2 : Y3;
  const int i0 = (blockIdx.x * 256 + threadIdx.x) * 8;
  f32x4 a = *(const f32x4*)(W + i0);
  f32x4 b = *(const f32x4*)(W + i0 + 4);
  u16x8 o;
#pragma unroll
  for (int j = 0; j < 4; ++j) { o[j] = f2bf(a[j]); o[4 + j] = f2bf(b[j]); }
  *(u16x8*)(Y + i0) = o;
}

__global__ __launch_bounds__(256) void cvt_mt(const float* __restrict__ X,
                                              u16* __restrict__ Y) {
  const int i0 = (blockIdx.x * 256 + threadIdx.x) * 8;
  f32x4 a = *(const f32x4*)(X + i0);
  f32x4 b = *(const f32x4*)(X + i0 + 4);
  u16x8 o;
#pragma unroll
  for (int j = 0; j < 4; ++j) { o[j] = f2bf(a[j]); o[4 + j] = f2bf(b[j]); }
  *(u16x8*)(Y + i0) = o;
}

// ---------- MFMA GEMM: C = Xbf @ Wbf^T + bias (both inputs k-contiguous) ----------
// 128x128 tile, BK=32, 4 waves each 64x64 (4x4 of 16x16x32 MFMA). m97 structure.
// EPI: 0 = fp32 out + bias; 1 = bf16 out + bias; 2 = bf16 out + bias + per-head softmax64.
template<int EPI>
__global__ __launch_bounds__(256) void gemm_mfma(const u16* __restrict__ X,
    const u16* __restrict__ W, const float* __restrict__ bias,
    void* __restrict__ Cout) {
  __shared__ __align__(16) u16 sA[128 * 32];
  __shared__ __align__(16) u16 sB[128 * 32];
  const int tid = threadIdx.x;
  const int w = tid >> 6, lane = tid & 63;
  const int bm = blockIdx.x * 128, bn = blockIdx.y * 128;
  const int wm = (w >> 1) * 64, wn = (w & 1) * 64;
  const int lrow = lane >> 2, lk = (lane & 3) * 8;  // staging: 16 rows/wave-inst
  const int fr = lane & 15, quad = lane >> 4;
  f32x4 acc[4][4] = {};
  for (int k0 = 0; k0 < E_; k0 += 32) {
    __syncthreads();                 // protect LDS from previous iter's readers
#pragma unroll
    for (int j = 0; j < 2; ++j) {
      const int rb = j * 64 + w * 16;
      async16(X + (size_t)(bm + rb + lrow) * E_ + k0 + lk, sA + rb * 32);
      async16(W + (size_t)(bn + rb + lrow) * E_ + k0 + lk, sB + rb * 32);
    }
    __syncthreads();                 // compiler emits vmcnt(0) before barrier
    bf16x8 af[4], bfr[4];
#pragma unroll
    for (int t = 0; t < 4; ++t) {
      af[t]  = *(const bf16x8*)(sA + (wm + t * 16 + fr) * 32 + quad * 8);
      bfr[t] = *(const bf16x8*)(sB + (wn + t * 16 + fr) * 32 + quad * 8);
    }
#pragma unroll
    for (int i = 0; i < 4; ++i)
#pragma unroll
      for (int j = 0; j < 4; ++j)
        acc[i][j] = __builtin_amdgcn_mfma_f32_16x16x32_bf16(af[i], bfr[j], acc[i][j], 0, 0, 0);
  }
  // epilogue: C/D layout col=lane&15, row=quad*4+reg (verified m89/m91)
  if (EPI == 0) {
    float* C = (float*)Cout;
#pragma unroll
    for (int i = 0; i < 4; ++i)
#pragma unroll
      for (int r = 0; r < 4; ++r) {
        const int row = bm + wm + i * 16 + quad * 4 + r;
#pragma unroll
        for (int j = 0; j < 4; ++j) {
          const int col = bn + wn + j * 16 + fr;
          C[(size_t)row * E_ + col] = acc[i][j][r] + bias[col];
        }
      }
  } else if (EPI == 1) {
    u16* C = (u16*)Cout;
#pragma unroll
    for (int i = 0; i < 4; ++i)
#pragma unroll
      for (int r = 0; r < 4; ++r) {
        const int row = bm + wm + i * 16 + quad * 4 + r;
#pragma unroll
        for (int j = 0; j < 4; ++j) {
          const int col = bn + wn + j * 16 + fr;
          C[(size_t)row * E_ + col] = f2bf(acc[i][j][r] + bias[col]);
        }
      }
  } else {
    // wave's 64 cols == exactly one head slice; softmax over (4 nt regs x 16 quad lanes)
    u16* C = (u16*)Cout;
#pragma unroll
    for (int i = 0; i < 4; ++i)
#pragma unroll
      for (int r = 0; r < 4; ++r) {
        float v[4];
#pragma unroll
        for (int j = 0; j < 4; ++j)
          v[j] = acc[i][j][r] + bias[bn + wn + j * 16 + fr];
        float mx = fmaxf(fmaxf(v[0], v[1]), fmaxf(v[2], v[3]));
#pragma unroll
        for (int off = 1; off < 16; off <<= 1) mx = fmaxf(mx, __shfl_xor(mx, off, 64));
        float e[4], s = 0.f;
#pragma unroll
        for (int j = 0; j < 4; ++j) { e[j] = __expf(v[j] - mx); s += e[j]; }
#pragma unroll
        for (int off = 1; off < 16; off <<= 1) s += __shfl_xor(s, off, 64);
        const float inv = 1.f / s;
        const int row = bm + wm + i * 16 + quad * 4 + r;
#pragma unroll
        for (int j = 0; j < 4; ++j)
          C[(size_t)row * E_ + bn + wn + j * 16 + fr] = f2bf(e[j] * inv);
      }
  }
}

// ---------- per-head reductions: Mt[n] = (K^T V)^T (i.e. Mt[e][d]), Ksum, Vsum ----------
__global__ __launch_bounds__(256) void kv_reduce(const u16* __restrict__ K,
    const u16* __restrict__ V, float* __restrict__ Mt, float* __restrict__ Ks,
    float* __restrict__ Vs) {
  const int n = blockIdx.x, b = n >> 3, h = n & 7;
  const int tid = threadIdx.x;
  const int td = tid & 15, te = tid >> 4;
  __shared__ float sK[16][64], sV[16][64];
  float acc[4][4] = {};
  float srow = 0.f;
  const int which = tid >> 7, sub = tid & 127;
  const int lr = sub >> 3, ck = (sub & 7) * 8;
  const u16* src = which ? V : K;
  const int l0beg = blockIdx.y * (L_ / 8);
  for (int l0 = l0beg; l0 < l0beg + L_ / 8; l0 += 16) {
    u16x8 d8 = *(const u16x8*)(src + (size_t)((l0 + lr) * B_ + b) * E_ + h * 64 + ck);
    __syncthreads();
    float* dst = which ? &sV[lr][ck] : &sK[lr][ck];
#pragma unroll
    for (int j = 0; j < 8; ++j) dst[j] = bf2f(d8[j]);
    __syncthreads();
#pragma unroll 4
    for (int p = 0; p < 16; ++p) {
      f32x4 kk = *(const f32x4*)&sK[p][td * 4];
      f32x4 vv = *(const f32x4*)&sV[p][te * 4];
#pragma unroll
      for (int i = 0; i < 4; ++i)
#pragma unroll
        for (int j = 0; j < 4; ++j)
          acc[i][j] = fmaf(kk[i], vv[j], acc[i][j]);
      if (tid < 64) srow += sK[p][tid];
      else if (tid < 128) srow += sV[p][tid - 64];
    }
  }
#pragma unroll
  for (int i = 0; i < 4; ++i)
#pragma unroll
    for (int j = 0; j < 4; ++j)
      atomicAdd(&Mt[n * 4096 + (te * 4 + j) * 64 + td * 4 + i], acc[i][j]);
  if (tid < 64) atomicAdd(&Ks[n * 64 + tid], srow);
  else if (tid < 128) atomicAdd(&Vs[n * 64 + tid - 64], srow);
}

// ---------- apply: A = (2*Q@M + 62*Vsum) / den, den = 2*q.Ksum + 62*L ----------
// One block per (head n, 128-row chunk). B-operand = Mtbf (= M^T, k-contiguous).
__global__ __launch_bounds__(256) void apply_mfma(const u16* __restrict__ Qbf,
    const u16* __restrict__ Mtbf, const float* __restrict__ Ksum,
    const float* __restrict__ Vsum, u16* __restrict__ Abf) {
  __shared__ __align__(16) u16 sQ[128 * 64];
  __shared__ __align__(16) u16 sM[64 * 64];
  __shared__ float sKs[64], sVs[64], sDen[128];
  const int n = blockIdx.x, b = n >> 3, h = n & 7;
  const int l0 = blockIdx.y * 128;
  const int tid = threadIdx.x, w = tid >> 6, lane = tid & 63;
  const int fr = lane & 15, quad = lane >> 4;
  // stage Q rows (global rows r = l*4+b, 64 bf16 each)
#pragma unroll
  for (int j = 0; j < 4; ++j) {
    const int rloc = w * 32 + j * 8;
    const int row = rloc + (lane >> 3);
    const int k = (lane & 7) * 8;
    async16(Qbf + (size_t)((l0 + row) * B_ + b) * E_ + h * 64 + k, sQ + rloc * 64);
  }
#pragma unroll
  for (int j = 0; j < 2; ++j) {
    const int base = (w * 2 + j) * 512;
    async16(Mtbf + (size_t)n * 4096 + base + lane * 8, sM + base);
  }
  if (tid < 64) sKs[tid] = Ksum[n * 64 + tid];
  else if (tid < 128) sVs[tid - 64] = Vsum[n * 64 + tid - 64];
  __syncthreads();
  // fragments (wave w owns rows w*32..w*32+31 -> 2 m-tiles; all 4 n-tiles; K=64 -> 2 k-steps)
  union { u16x8 u; bf16x8 bv; } aU[2][2];
  bf16x8 bF[4][2];
#pragma unroll
  for (int mt = 0; mt < 2; ++mt)
#pragma unroll
    for (int ks = 0; ks < 2; ++ks)
      aU[mt][ks].u = *(const u16x8*)(sQ + (w * 32 + mt * 16 + fr) * 64 + ks * 32 + quad * 8);
#pragma unroll
  for (int nt = 0; nt < 4; ++nt)
#pragma unroll
    for (int ks = 0; ks < 2; ++ks)
      bF[nt][ks] = *(const bf16x8*)(sM + (nt * 16 + fr) * 64 + ks * 32 + quad * 8);
  // denominator from A-fragments: den = 2*q.Ksum + 62*L (quads hold disjoint k-ranges)
  float pden[2] = {0.f, 0.f};
#pragma unroll
  for (int mt = 0; mt < 2; ++mt)
#pragma unroll
    for (int ks = 0; ks < 2; ++ks)
#pragma unroll
      for (int j = 0; j < 8; ++j)
        pden[mt] = fmaf(bf2f(aU[mt][ks].u[j]), sKs[ks * 32 + quad * 8 + j], pden[mt]);
#pragma unroll
  for (int mt = 0; mt < 2; ++mt) {
    pden[mt] += __shfl_xor(pden[mt], 16, 64);
    pden[mt] += __shfl_xor(pden[mt], 32, 64);
    if (quad == 0)
      sDen[w * 32 + mt * 16 + fr] = fmaxf(2.f * pden[mt] + 62.f * (float)L_, 1e-6f);
  }
  __syncthreads();
  // MFMA with acc init = 31*Vsum[col]  ->  2*acc/den = (2QM + 62Vsum)/den
  f32x4 acc[2][4];
#pragma unroll
  for (int mt = 0; mt < 2; ++mt)
#pragma unroll
    for (int nt = 0; nt < 4; ++nt) {
      const float iv = 31.f * sVs[nt * 16 + fr];
      acc[mt][nt] = (f32x4){iv, iv, iv, iv};
#pragma unroll
      for (int ks = 0; ks < 2; ++ks)
        acc[mt][nt] = __builtin_amdgcn_mfma_f32_16x16x32_bf16(aU[mt][ks].bv, bF[nt][ks],
                                                              acc[mt][nt], 0, 0, 0);
    }
#pragma unroll
  for (int mt = 0; mt < 2; ++mt)
#pragma unroll
    for (int r = 0; r < 4; ++r) {
      const int rloc = w * 32 + mt * 16 + quad * 4 + r;
      const float invd = 2.f / sDen[rloc];
      const size_t orow = (size_t)((l0 + rloc) * B_ + b) * E_ + h * 64;
#pragma unroll
      for (int nt = 0; nt < 4; ++nt)
        Abf[orow + nt * 16 + fr] = f2bf(acc[mt][nt][r] * invd);
    }
}

extern "C" void kernel_launch(void* const* d_in, const int* in_sizes, int n_in,
                              void* d_out, int out_size, void* d_ws, size_t ws_size,
                              hipStream_t stream) {
  const float* query = (const float*)d_in[0];
  const float* Wq = (const float*)d_in[1];
  const float* bq = (const float*)d_in[2];
  const float* Wk = (const float*)d_in[3];
  const float* bk = (const float*)d_in[4];
  const float* Wv = (const float*)d_in[5];
  const float* bv = (const float*)d_in[6];
  const float* Wo = (const float*)d_in[7];
  const float* bo = (const float*)d_in[8];
  float* out = (float*)d_out;

  char* ws = (char*)d_ws;
  u16* Xbf  = (u16*)(ws);                        // 8 MB
  u16* Qbf  = (u16*)(ws + 8388608);
  u16* Kbf  = (u16*)(ws + 16777216);
  u16* Vbf  = (u16*)(ws + 25165824);
  u16* Abf  = (u16*)(ws + 33554432);
  u16* Wqb  = (u16*)(ws + 41943040);             // 512 KB each
  u16* Wkb  = (u16*)(ws + 42467328);
  u16* Wvb  = (u16*)(ws + 42991616);
  u16* Wob  = (u16*)(ws + 43515904);
  u16* Mtbf = (u16*)(ws + 44040192);             // 256 KB
  float* Mt = (float*)(ws + 44302336);           // 512 KB
  float* Ks = (float*)(ws + 44826624);           // 8 KB
  float* Vs = (float*)(ws + 44834816);           // 8 KB

  cvt_x<<<SZ / 2048, 256, 0, stream>>>(query, Xbf);
  cvt_w<<<dim3(128, 4), 256, 0, stream>>>(Wq, Wk, Wv, Wo, Wqb, Wkb, Wvb, Wob);
  hipMemsetAsync(Mt, 0, (size_t)(NH * 4096 + 2 * NH * 64) * sizeof(float), stream);

  dim3 gg(NROW / 128, E_ / 128);
  gemm_mfma<2><<<gg, 256, 0, stream>>>(Xbf, Wqb, bq, Qbf);   // Q + softmax
  gemm_mfma<2><<<gg, 256, 0, stream>>>(Xbf, Wkb, bk, Kbf);   // K + softmax
  gemm_mfma<1><<<gg, 256, 0, stream>>>(Xbf, Wvb, bv, Vbf);   // V

  kv_reduce<<<dim3(NH, 8), 256, 0, stream>>>(Kbf, Vbf, Mt, Ks, Vs);
  cvt_mt<<<(NH * 4096) / 2048, 256, 0, stream>>>(Mt, Mtbf);
  apply_mfma<<<dim3(NH, L_ / 128), 256, 0, stream>>>(Qbf, Mtbf, Ks, Vs, Abf);

  gemm_mfma<0><<<gg, 256, 0, stream>>>(Abf, Wob, bo, out);   // output projection
}